// Round 1
// baseline (757.231 us; speedup 1.0000x reference)
//
#include <hip/hip_runtime.h>
#include <hip/hip_bf16.h>

typedef __hip_bfloat16 bf16;

// Problem constants: N=M=2048, APP_IN=512, HEADS=8, dh=128, dv=64.

__device__ __forceinline__ void unpack8(uint4 u, float f[8]) {
  union { unsigned int b; float v; } t;
  t.b = u.x << 16;          f[0] = t.v;
  t.b = u.x & 0xffff0000u;  f[1] = t.v;
  t.b = u.y << 16;          f[2] = t.v;
  t.b = u.y & 0xffff0000u;  f[3] = t.v;
  t.b = u.z << 16;          f[4] = t.v;
  t.b = u.z & 0xffff0000u;  f[5] = t.v;
  t.b = u.w << 16;          f[6] = t.v;
  t.b = u.w & 0xffff0000u;  f[7] = t.v;
}

// C[2048,N] = X[2048,512] @ W[512,N] + bias, stored bf16.
// 64x64 block tile, BK=16, 256 threads, 4x4 microtile.
__global__ __launch_bounds__(256)
void proj_gemm_kernel(const float* __restrict__ X, const float* __restrict__ W,
                      const float* __restrict__ bias, bf16* __restrict__ C, int N)
{
  __shared__ float As[16][68];   // pad 68: 272B row = 17x16B -> conflict-free b128 reads
  __shared__ float Bs[16][64];
  const int K = 512;
  int tid = threadIdx.x;
  int bm = blockIdx.y * 64;
  int bn = blockIdx.x * 64;
  int lm  = tid >> 2;            // A-load row 0..63
  int lk  = (tid & 3) << 2;      // A-load k quad
  int lkb = tid >> 4;            // B-load k 0..15
  int lnb = (tid & 15) << 2;     // B-load n quad
  int tm  = (tid >> 4) << 2;     // compute row base
  int tn  = (tid & 15) << 2;     // compute col base
  float acc[4][4] = {{0.f, 0.f, 0.f, 0.f}, {0.f, 0.f, 0.f, 0.f},
                     {0.f, 0.f, 0.f, 0.f}, {0.f, 0.f, 0.f, 0.f}};
  for (int k0 = 0; k0 < K; k0 += 16) {
    float4 av = *(const float4*)(X + (size_t)(bm + lm) * K + k0 + lk);
    float4 bv = *(const float4*)(W + (size_t)(k0 + lkb) * N + bn + lnb);
    __syncthreads();
    As[lk + 0][lm] = av.x;
    As[lk + 1][lm] = av.y;
    As[lk + 2][lm] = av.z;
    As[lk + 3][lm] = av.w;
    *(float4*)&Bs[lkb][lnb] = bv;
    __syncthreads();
#pragma unroll
    for (int k = 0; k < 16; ++k) {
      float4 a = *(const float4*)&As[k][tm];
      float4 b = *(const float4*)&Bs[k][tn];
      float aa[4] = {a.x, a.y, a.z, a.w};
      float bb[4] = {b.x, b.y, b.z, b.w};
#pragma unroll
      for (int i = 0; i < 4; ++i)
#pragma unroll
        for (int j = 0; j < 4; ++j)
          acc[i][j] += aa[i] * bb[j];
    }
  }
  float4 bvv = *(const float4*)(bias + bn + tn);
  float bb[4] = {bvv.x, bvv.y, bvv.z, bvv.w};
#pragma unroll
  for (int i = 0; i < 4; ++i) {
    bf16* cp = C + (size_t)(bm + tm + i) * N + bn + tn;
#pragma unroll
    for (int j = 0; j < 4; ++j)
      cp[j] = __float2bfloat16(acc[i][j] + bb[j]);
  }
}

// Fused attention: per (head, 32-row m-tile) block; single pass over n
// (no max-subtraction in reference softmax, scores ~1e-5, exp never overflows).
// Q/G2 row norms computed in-kernel; scale invnorm/128 folded into dot products.
__global__ __launch_bounds__(256)
void attn_kernel(const bf16* __restrict__ Kb, const bf16* __restrict__ G1b,
                 const bf16* __restrict__ Vb, const bf16* __restrict__ Qb,
                 const bf16* __restrict__ G2b, float* __restrict__ out)
{
  // bf16-bit tiles, row stride 136 (272B = 17x16B -> b128 reads rotate bank quads)
  __shared__ unsigned short Qs[32][136];
  __shared__ unsigned short G2s[32][136];
  __shared__ unsigned short Ks[32][136];
  __shared__ unsigned short G1s[32][136];
  __shared__ float Vs[32][68];   // pad 68 breaks store conflicts
  __shared__ float Es[32][33];   // scores; also reduction scratch
  __shared__ float sQ[32];
  __shared__ float sG[32];

  int tid = threadIdx.x;
  int h  = blockIdx.y;
  int m0 = blockIdx.x * 32;

  int r  = tid >> 3;          // 0..31 (tile row for loads)
  int c8 = (tid & 7) << 4;    // 0..112 (16 bf16 per thread per row)
  int vd = (tid & 7) << 3;    // 0..56  (V columns)

  // ---- load Q, G2 tiles; accumulate norm partials from registers ----
  const uint4* qp  = (const uint4*)(Qb  + (size_t)(m0 + r) * 1024 + h * 128 + c8);
  const uint4* g2p = (const uint4*)(G2b + (size_t)(m0 + r) * 1024 + h * 128 + c8);
  uint4 q0 = qp[0],  q1 = qp[1];
  uint4 g0 = g2p[0], g1 = g2p[1];
  *(uint4*)&Qs[r][c8]      = q0;
  *(uint4*)&Qs[r][c8 + 8]  = q1;
  *(uint4*)&G2s[r][c8]     = g0;
  *(uint4*)&G2s[r][c8 + 8] = g1;
  float sq = 0.f, sg = 0.f;
  {
    float f[8];
    unpack8(q0, f);
#pragma unroll
    for (int j = 0; j < 8; ++j) sq += f[j] * f[j];
    unpack8(q1, f);
#pragma unroll
    for (int j = 0; j < 8; ++j) sq += f[j] * f[j];
    unpack8(g0, f);
#pragma unroll
    for (int j = 0; j < 8; ++j) sg += f[j] * f[j];
    unpack8(g1, f);
#pragma unroll
    for (int j = 0; j < 8; ++j) sg += f[j] * f[j];
  }
  Es[r][tid & 7]     = sq;
  Es[r][8 + (tid & 7)] = sg;
  __syncthreads();
  if (tid < 32) {
    float s1 = 0.f, s2 = 0.f;
#pragma unroll
    for (int c = 0; c < 8; ++c) { s1 += Es[tid][c]; s2 += Es[tid][8 + c]; }
    sQ[tid] = rsqrtf(s1) * 0.0078125f;  // invnorm / dh
    sG[tid] = rsqrtf(s2) * 0.0078125f;
  }

  // score-phase mapping: thread (rg,cg) handles m in {rg, rg+16}, n in {cg, cg+16}
  int rg = tid >> 4;      // 0..15
  int cg = tid & 15;      // 0..15
  int mA = rg, mB = rg + 16;
  int nA = cg, nB = cg + 16;
  // PV mapping: row pr, 8 value-dims at pd
  int pr = tid >> 3;
  int pd = (tid & 7) << 3;

  float acc[8] = {0.f, 0.f, 0.f, 0.f, 0.f, 0.f, 0.f, 0.f};
  float dp0 = 0.f, dp1 = 0.f;   // denominator partials for rows mA, mB

  for (int nt = 0; nt < 64; ++nt) {
    int n0 = nt * 32;
    const uint4* kp  = (const uint4*)(Kb  + (size_t)(n0 + r) * 1024 + h * 128 + c8);
    const uint4* g1p = (const uint4*)(G1b + (size_t)(n0 + r) * 1024 + h * 128 + c8);
    uint4 k0v = kp[0],  k1v = kp[1];
    uint4 h0v = g1p[0], h1v = g1p[1];
    uint4 vv = *(const uint4*)(Vb + (size_t)(n0 + r) * 512 + h * 64 + vd);
    __syncthreads();   // previous PV (Es/Vs readers) done
    *(uint4*)&Ks[r][c8]      = k0v;
    *(uint4*)&Ks[r][c8 + 8]  = k1v;
    *(uint4*)&G1s[r][c8]     = h0v;
    *(uint4*)&G1s[r][c8 + 8] = h1v;
    {
      float vf[8];
      unpack8(vv, vf);
      *(float4*)&Vs[r][vd]     = make_float4(vf[0], vf[1], vf[2], vf[3]);
      *(float4*)&Vs[r][vd + 4] = make_float4(vf[4], vf[5], vf[6], vf[7]);
    }
    __syncthreads();

    // ---- score phase: two 2x2 dot blocks over d=128 ----
    float dA00 = 0.f, dA01 = 0.f, dA10 = 0.f, dA11 = 0.f;
#pragma unroll 2
    for (int d = 0; d < 128; d += 8) {
      float qa[8], qb[8], ka[8], kb[8];
      unpack8(*(const uint4*)&Qs[mA][d], qa);
      unpack8(*(const uint4*)&Qs[mB][d], qb);
      unpack8(*(const uint4*)&Ks[nA][d], ka);
      unpack8(*(const uint4*)&Ks[nB][d], kb);
#pragma unroll
      for (int j = 0; j < 8; ++j) {
        dA00 += qa[j] * ka[j]; dA01 += qa[j] * kb[j];
        dA10 += qb[j] * ka[j]; dA11 += qb[j] * kb[j];
      }
    }
    float dG00 = 0.f, dG01 = 0.f, dG10 = 0.f, dG11 = 0.f;
#pragma unroll 2
    for (int d = 0; d < 128; d += 8) {
      float ga[8], gb[8], ha[8], hb[8];
      unpack8(*(const uint4*)&G2s[mA][d], ga);
      unpack8(*(const uint4*)&G2s[mB][d], gb);
      unpack8(*(const uint4*)&G1s[nA][d], ha);
      unpack8(*(const uint4*)&G1s[nB][d], hb);
#pragma unroll
      for (int j = 0; j < 8; ++j) {
        dG00 += ga[j] * ha[j]; dG01 += ga[j] * hb[j];
        dG10 += gb[j] * ha[j]; dG11 += gb[j] * hb[j];
      }
    }
    float aA = sQ[mA], aB = sQ[mB], gsA = sG[mA], gsB = sG[mB];
    float e00 = __expf(dA00 * aA * dG00 * gsA);
    float e01 = __expf(dA01 * aA * dG01 * gsA);
    float e10 = __expf(dA10 * aB * dG10 * gsB);
    float e11 = __expf(dA11 * aB * dG11 * gsB);
    Es[mA][nA] = e00; Es[mA][nB] = e01;
    Es[mB][nA] = e10; Es[mB][nB] = e11;
    dp0 += e00 + e01;
    dp1 += e10 + e11;
    __syncthreads();

    // ---- PV phase: acc[pr][pd..pd+7] += e * V ----
#pragma unroll 4
    for (int n = 0; n < 32; ++n) {
      float e = Es[pr][n];
      float4 v0 = *(const float4*)&Vs[n][pd];
      float4 v1 = *(const float4*)&Vs[n][pd + 4];
      acc[0] += e * v0.x; acc[1] += e * v0.y;
      acc[2] += e * v0.z; acc[3] += e * v0.w;
      acc[4] += e * v1.x; acc[5] += e * v1.y;
      acc[6] += e * v1.z; acc[7] += e * v1.w;
    }
  }

  // ---- denominator reduction (16 partials per row) + output ----
  __syncthreads();
  Es[mA][cg] = dp0;
  Es[mB][cg] = dp1;
  __syncthreads();
  if (tid < 32) {
    float s = 0.f;
#pragma unroll
    for (int c = 0; c < 16; ++c) s += Es[tid][c];
    sQ[tid] = 1.0f / s;
  }
  __syncthreads();
  float inv = sQ[pr];
  float* op = out + (size_t)(m0 + pr) * 512 + h * 64 + pd;
  *(float4*)op       = make_float4(acc[0] * inv, acc[1] * inv, acc[2] * inv, acc[3] * inv);
  *(float4*)(op + 4) = make_float4(acc[4] * inv, acc[5] * inv, acc[6] * inv, acc[7] * inv);
}

extern "C" void kernel_launch(void* const* d_in, const int* in_sizes, int n_in,
                              void* d_out, int out_size, void* d_ws, size_t ws_size,
                              hipStream_t stream) {
  const float* first_app  = (const float*)d_in[0];
  const float* first_pos  = (const float*)d_in[1];
  const float* second_app = (const float*)d_in[2];
  const float* second_pos = (const float*)d_in[3];
  const float* WK  = (const float*)d_in[4];
  const float* bK  = (const float*)d_in[5];
  const float* WQ  = (const float*)d_in[6];
  const float* bQ  = (const float*)d_in[7];
  const float* WV  = (const float*)d_in[8];
  const float* bV  = (const float*)d_in[9];
  const float* WG1 = (const float*)d_in[10];
  const float* bG1 = (const float*)d_in[11];
  const float* WG2 = (const float*)d_in[12];
  const float* bG2 = (const float*)d_in[13];

  // workspace: bf16 intermediates, 9,437,184 elems = 18 MB
  bf16* ws  = (bf16*)d_ws;
  bf16* Kb  = ws;                        // [2048,1024]
  bf16* Qb  = ws + (size_t)2097152;      // [2048,1024]
  bf16* G1b = ws + (size_t)2 * 2097152;  // [2048,1024]
  bf16* G2b = ws + (size_t)3 * 2097152;  // [2048,1024]
  bf16* Vb  = ws + (size_t)4 * 2097152;  // [2048,512]

  dim3 blk(256);
  proj_gemm_kernel<<<dim3(16, 32), blk, 0, stream>>>(first_app,  WK,  bK,  Kb,  1024);
  proj_gemm_kernel<<<dim3(16, 32), blk, 0, stream>>>(second_app, WQ,  bQ,  Qb,  1024);
  proj_gemm_kernel<<<dim3(16, 32), blk, 0, stream>>>(first_pos,  WG1, bG1, G1b, 1024);
  proj_gemm_kernel<<<dim3(16, 32), blk, 0, stream>>>(second_pos, WG2, bG2, G2b, 1024);
  proj_gemm_kernel<<<dim3(8, 32),  blk, 0, stream>>>(first_app,  WV,  bV,  Vb,  512);

  attn_kernel<<<dim3(64, 8), blk, 0, stream>>>(Kb, G1b, Vb, Qb, G2b, (float*)d_out);
}

// Round 2
// 306.333 us; speedup vs baseline: 2.4719x; 2.4719x over previous
//
#include <hip/hip_runtime.h>
#include <hip/hip_bf16.h>

typedef __hip_bfloat16 bf16;
typedef __attribute__((ext_vector_type(8))) short short8;   // 8 bf16 = one MFMA A/B frag
typedef __attribute__((ext_vector_type(4))) float f32x4;    // MFMA C/D frag

#define MFMA(a, b, c) __builtin_amdgcn_mfma_f32_16x16x32_bf16(a, b, c, 0, 0, 0)

static __device__ __forceinline__ float b2f(unsigned short u) {
  union { unsigned u; float f; } t; t.u = ((unsigned)u) << 16; return t.f;
}
static __device__ __forceinline__ unsigned short f2bf(float f) {
  union { float f; unsigned u; } t; t.f = f;
  unsigned r = t.u + 0x7fffu + ((t.u >> 16) & 1u);   // RNE
  return (unsigned short)(r >> 16);
}

// C[2048,N] = X[2048,512] @ W[512,N] + bias, stored bf16.
// TRANS=false: C row-major [2048][N]. TRANS=true: C[N][2048] (transposed, for V).
template <bool TRANS>
__global__ __launch_bounds__(256)
void proj_gemm_kernel(const float* __restrict__ X, const float* __restrict__ W,
                      const float* __restrict__ bias, bf16* __restrict__ C, int N)
{
  __shared__ float As[16][68];
  __shared__ float Bs[16][64];
  const int K = 512;
  int tid = threadIdx.x;
  int bm = blockIdx.y * 64;
  int bn = blockIdx.x * 64;
  int lm  = tid >> 2;
  int lk  = (tid & 3) << 2;
  int lkb = tid >> 4;
  int lnb = (tid & 15) << 2;
  int tm  = (tid >> 4) << 2;
  int tn  = (tid & 15) << 2;
  float acc[4][4] = {{0.f,0.f,0.f,0.f},{0.f,0.f,0.f,0.f},{0.f,0.f,0.f,0.f},{0.f,0.f,0.f,0.f}};
  for (int k0 = 0; k0 < K; k0 += 16) {
    float4 av = *(const float4*)(X + (size_t)(bm + lm) * K + k0 + lk);
    float4 bv = *(const float4*)(W + (size_t)(k0 + lkb) * N + bn + lnb);
    __syncthreads();
    As[lk + 0][lm] = av.x;
    As[lk + 1][lm] = av.y;
    As[lk + 2][lm] = av.z;
    As[lk + 3][lm] = av.w;
    *(float4*)&Bs[lkb][lnb] = bv;
    __syncthreads();
#pragma unroll
    for (int k = 0; k < 16; ++k) {
      float4 a = *(const float4*)&As[k][tm];
      float4 b = *(const float4*)&Bs[k][tn];
      float aa[4] = {a.x, a.y, a.z, a.w};
      float bb[4] = {b.x, b.y, b.z, b.w};
#pragma unroll
      for (int i = 0; i < 4; ++i)
#pragma unroll
        for (int j = 0; j < 4; ++j)
          acc[i][j] += aa[i] * bb[j];
    }
  }
  float4 bvv = *(const float4*)(bias + bn + tn);
  float bb[4] = {bvv.x, bvv.y, bvv.z, bvv.w};
  if (TRANS) {
    // C_t[col][row], row stride 2048: C_t[bn+tn+j][bm+tm+i]
#pragma unroll
    for (int j = 0; j < 4; ++j) {
      unsigned short s0 = f2bf(acc[0][j] + bb[j]);
      unsigned short s1 = f2bf(acc[1][j] + bb[j]);
      unsigned short s2 = f2bf(acc[2][j] + bb[j]);
      unsigned short s3 = f2bf(acc[3][j] + bb[j]);
      uint2 pw;
      pw.x = (unsigned)s0 | ((unsigned)s1 << 16);
      pw.y = (unsigned)s2 | ((unsigned)s3 << 16);
      *(uint2*)((unsigned short*)C + (size_t)(bn + tn + j) * 2048 + bm + tm) = pw;
    }
  } else {
#pragma unroll
    for (int i = 0; i < 4; ++i) {
      bf16* cp = C + (size_t)(bm + tm + i) * N + bn + tn;
#pragma unroll
      for (int j = 0; j < 4; ++j)
        cp[j] = __float2bfloat16(acc[i][j] + bb[j]);
    }
  }
}

// MFMA fused attention.
// Block: 256 thr / 4 waves; wave w owns m-rows [m0+16w, m0+16w+16). Ntile=64.
// Scores via 16x16x32 bf16 MFMA (A=Q/G2 row frags in regs, B=K/G1 rows from LDS).
// P' = exp(x)-1 stored bf16 in per-wave LDS scratch (C/D->A layout round trip).
// O = (sum_n V + sum_n P'·V) / (2048 + sum_n P'); denom via ones-B-frag MFMA
// so it lands in the same C/D row layout as O (no cross-lane reduction).
__global__ __launch_bounds__(256)
void attn_mfma_kernel(const bf16* __restrict__ Kb, const bf16* __restrict__ G1b,
                      const bf16* __restrict__ Vtg, const bf16* __restrict__ Qb,
                      const bf16* __restrict__ G2b, float* __restrict__ out)
{
  __shared__ short Ks[64][136];    // pad: stride 272B = 17 quads, balanced b128
  __shared__ short G1s[64][136];
  __shared__ short Vts[64][72];    // Vt[j][n], stride 144B = 9 quads
  __shared__ short Ps[4][64][20];  // per-wave P' col-major [n][m], stride 40B
  __shared__ float scaleS[64];
  __shared__ float Vp[64][4];
  __shared__ float Vsum[64];

  const int tid = threadIdx.x;
  const int w   = tid >> 6;
  const int l   = tid & 63;
  const int l15 = l & 15;
  const int l4  = l >> 4;
  const int h   = blockIdx.y;
  const int m0  = blockIdx.x * 64;

  // ---- persistent Q/G2 A-fragments: lane holds row (l15), k = l4*8 + 32*kk ----
  short8 qf[4], gf[4];
  {
    const size_t ro = (size_t)(m0 + w * 16 + l15) * 1024 + h * 128 + l4 * 8;
#pragma unroll
    for (int kk = 0; kk < 4; ++kk) {
      qf[kk] = *(const short8*)(Qb + ro + kk * 32);
      gf[kk] = *(const short8*)(G2b + ro + kk * 32);
    }
  }
  // ---- row norms -> per-row scale = 1/(||Q||*||G2||*128*128) ----
  {
    float sq = 0.f, sg = 0.f;
#pragma unroll
    for (int kk = 0; kk < 4; ++kk)
#pragma unroll
      for (int j = 0; j < 8; ++j) {
        float q = b2f((unsigned short)qf[kk][j]);
        float g = b2f((unsigned short)gf[kk][j]);
        sq += q * q; sg += g * g;
      }
    sq += __shfl_xor(sq, 16, 64); sq += __shfl_xor(sq, 32, 64);
    sg += __shfl_xor(sg, 16, 64); sg += __shfl_xor(sg, 32, 64);
    float sc = rsqrtf(sq) * rsqrtf(sg) * (1.0f / 16384.0f);
    if (l < 16) scaleS[w * 16 + l] = sc;
  }

  const int r0 = tid >> 3, c0 = (tid & 7) * 16;   // K/G1 staging map
  const int jv = tid >> 2, nv = (tid & 3) * 16;   // Vt staging map

  short8 pk[4], pg[4], pv0, pv1;
  auto load_tile = [&](int nt) {
    const int n0 = nt * 64;
    const bf16* kp = Kb  + (size_t)(n0 + r0) * 1024 + h * 128 + c0;
    const bf16* gp = G1b + (size_t)(n0 + r0) * 1024 + h * 128 + c0;
    pk[0] = *(const short8*)(kp);
    pk[1] = *(const short8*)(kp + 8);
    pk[2] = *(const short8*)(kp + 32 * 1024);
    pk[3] = *(const short8*)(kp + 32 * 1024 + 8);
    pg[0] = *(const short8*)(gp);
    pg[1] = *(const short8*)(gp + 8);
    pg[2] = *(const short8*)(gp + 32 * 1024);
    pg[3] = *(const short8*)(gp + 32 * 1024 + 8);
    const bf16* vp = Vtg + (size_t)(h * 64 + jv) * 2048 + n0 + nv;
    pv0 = *(const short8*)(vp);
    pv1 = *(const short8*)(vp + 8);
  };
  load_tile(0);

  const f32x4 zero = {0.f, 0.f, 0.f, 0.f};
  f32x4 accO[4], accD = zero;
#pragma unroll
  for (int t = 0; t < 4; ++t) accO[t] = zero;
  float vsum_part = 0.f;

  short8 ones;
#pragma unroll
  for (int j = 0; j < 8; ++j) ones[j] = (short)0x3F80;  // bf16 1.0

  f32x4 s4 = zero;

  for (int nt = 0; nt < 32; ++nt) {
    __syncthreads();
    *(short8*)&Ks[r0][c0]           = pk[0];
    *(short8*)&Ks[r0][c0 + 8]       = pk[1];
    *(short8*)&Ks[r0 + 32][c0]      = pk[2];
    *(short8*)&Ks[r0 + 32][c0 + 8]  = pk[3];
    *(short8*)&G1s[r0][c0]          = pg[0];
    *(short8*)&G1s[r0][c0 + 8]      = pg[1];
    *(short8*)&G1s[r0 + 32][c0]     = pg[2];
    *(short8*)&G1s[r0 + 32][c0 + 8] = pg[3];
    *(short8*)&Vts[jv][nv]          = pv0;
    *(short8*)&Vts[jv][nv + 8]      = pv1;
#pragma unroll
    for (int j = 0; j < 8; ++j)
      vsum_part += b2f((unsigned short)pv0[j]) + b2f((unsigned short)pv1[j]);
    __syncthreads();
    if (nt == 0) s4 = *(const f32x4*)&scaleS[w * 16 + l4 * 4];
    if (nt + 1 < 32) load_tile(nt + 1);   // prefetch overlaps compute

    // ---- scores: SA = Q·K^T, SG = G2·G1^T (16m x 64n per wave) ----
    f32x4 sa[4], sg2[4];
#pragma unroll
    for (int t = 0; t < 4; ++t) { sa[t] = zero; sg2[t] = zero; }
#pragma unroll
    for (int t = 0; t < 4; ++t) {
#pragma unroll
      for (int kk = 0; kk < 4; ++kk) {
        short8 kbf = *(const short8*)&Ks[t * 16 + l15][kk * 32 + l4 * 8];
        sa[t]  = MFMA(qf[kk], kbf, sa[t]);
        short8 gbf = *(const short8*)&G1s[t * 16 + l15][kk * 32 + l4 * 8];
        sg2[t] = MFMA(gf[kk], gbf, sg2[t]);
      }
    }
    // ---- P' = exp(SA*SG*scale) - 1, bf16, to per-wave scratch ----
#pragma unroll
    for (int t = 0; t < 4; ++t) {
      unsigned short e0 = f2bf(__expf(sa[t][0] * sg2[t][0] * s4[0]) - 1.0f);
      unsigned short e1 = f2bf(__expf(sa[t][1] * sg2[t][1] * s4[1]) - 1.0f);
      unsigned short e2 = f2bf(__expf(sa[t][2] * sg2[t][2] * s4[2]) - 1.0f);
      unsigned short e3 = f2bf(__expf(sa[t][3] * sg2[t][3] * s4[3]) - 1.0f);
      uint2 pw;
      pw.x = (unsigned)e0 | ((unsigned)e1 << 16);
      pw.y = (unsigned)e2 | ((unsigned)e3 << 16);
      *(uint2*)&Ps[w][t * 16 + l15][l4 * 4] = pw;   // [n=col][m rows 4q..4q+3]
    }
    // ---- PV: O += P'·V ; denom += P'·ones (same-wave LDS RAW, no barrier) ----
#pragma unroll
    for (int ks = 0; ks < 2; ++ks) {
      short8 pf;
#pragma unroll
      for (int j = 0; j < 8; ++j)
        pf[j] = Ps[w][ks * 32 + l4 * 8 + j][l15];   // A[m=l15][n-contig]
      accD = MFMA(pf, ones, accD);
#pragma unroll
      for (int jt = 0; jt < 4; ++jt) {
        short8 vbf = *(const short8*)&Vts[jt * 16 + l15][ks * 32 + l4 * 8];
        accO[jt] = MFMA(pf, vbf, accO[jt]);
      }
    }
  }

  // ---- Vsum reduction (4 partials per j) ----
  __syncthreads();
  Vp[jv][tid & 3] = vsum_part;
  __syncthreads();
  if (tid < 64) Vsum[tid] = Vp[tid][0] + Vp[tid][1] + Vp[tid][2] + Vp[tid][3];
  __syncthreads();

  float inv[4];
#pragma unroll
  for (int r = 0; r < 4; ++r) inv[r] = 1.0f / (2048.0f + accD[r]);
#pragma unroll
  for (int jt = 0; jt < 4; ++jt) {
    float vs = Vsum[jt * 16 + l15];
#pragma unroll
    for (int r = 0; r < 4; ++r)
      out[(size_t)(m0 + w * 16 + l4 * 4 + r) * 512 + h * 64 + jt * 16 + l15]
        = (vs + accO[jt][r]) * inv[r];
  }
}

extern "C" void kernel_launch(void* const* d_in, const int* in_sizes, int n_in,
                              void* d_out, int out_size, void* d_ws, size_t ws_size,
                              hipStream_t stream) {
  const float* first_app  = (const float*)d_in[0];
  const float* first_pos  = (const float*)d_in[1];
  const float* second_app = (const float*)d_in[2];
  const float* second_pos = (const float*)d_in[3];
  const float* WK  = (const float*)d_in[4];
  const float* bK  = (const float*)d_in[5];
  const float* WQ  = (const float*)d_in[6];
  const float* bQ  = (const float*)d_in[7];
  const float* WV  = (const float*)d_in[8];
  const float* bV  = (const float*)d_in[9];
  const float* WG1 = (const float*)d_in[10];
  const float* bG1 = (const float*)d_in[11];
  const float* WG2 = (const float*)d_in[12];
  const float* bG2 = (const float*)d_in[13];

  bf16* ws  = (bf16*)d_ws;
  bf16* Kb  = ws;                        // [2048,1024]
  bf16* Qb  = ws + (size_t)2097152;      // [2048,1024]
  bf16* G1b = ws + (size_t)2 * 2097152;  // [2048,1024]
  bf16* G2b = ws + (size_t)3 * 2097152;  // [2048,1024]
  bf16* Vtg = ws + (size_t)4 * 2097152;  // [512,2048] = V^T (per-head rows)

  dim3 blk(256);
  proj_gemm_kernel<false><<<dim3(16, 32), blk, 0, stream>>>(first_app,  WK,  bK,  Kb,  1024);
  proj_gemm_kernel<false><<<dim3(16, 32), blk, 0, stream>>>(second_app, WQ,  bQ,  Qb,  1024);
  proj_gemm_kernel<false><<<dim3(16, 32), blk, 0, stream>>>(first_pos,  WG1, bG1, G1b, 1024);
  proj_gemm_kernel<false><<<dim3(16, 32), blk, 0, stream>>>(second_pos, WG2, bG2, G2b, 1024);
  proj_gemm_kernel<true ><<<dim3(8, 32),  blk, 0, stream>>>(first_app,  WV,  bV,  Vtg, 512);

  attn_mfma_kernel<<<dim3(32, 8), blk, 0, stream>>>(Kb, G1b, Vtg, Qb, G2b, (float*)d_out);
}

// Round 4
// 183.050 us; speedup vs baseline: 4.1368x; 1.6735x over previous
//
#include <hip/hip_runtime.h>
#include <hip/hip_bf16.h>

typedef __hip_bfloat16 bf16;
typedef __attribute__((ext_vector_type(8))) short short8;   // 8 bf16 = one MFMA A/B frag
typedef __attribute__((ext_vector_type(4))) float f32x4;    // MFMA C/D frag

#define MFMA(a, b, c) __builtin_amdgcn_mfma_f32_16x16x32_bf16(a, b, c, 0, 0, 0)

static __device__ __forceinline__ float b2f(unsigned short u) {
  union { unsigned u; float f; } t; t.u = ((unsigned)u) << 16; return t.f;
}
static __device__ __forceinline__ unsigned short f2bf(float f) {
  union { float f; unsigned u; } t; t.f = f;
  unsigned r = t.u + 0x7fffu + ((t.u >> 16) & 1u);   // RNE
  return (unsigned short)(r >> 16);
}
static __device__ __forceinline__ unsigned pack2(float a, float b) {
  return (unsigned)f2bf(a) | ((unsigned)f2bf(b) << 16);
}

// ---- workspace layout (bf16 element offsets) ----
#define KB_OFF   ((size_t)0)          // K  [2048][1024]
#define QB_OFF   ((size_t)2097152)    // Q  [2048][1024]
#define G1_OFF   ((size_t)4194304)    // G1 [2048][1024]
#define G2_OFF   ((size_t)6291456)    // G2 [2048][1024]
#define VT_OFF   ((size_t)8388608)    // V^T [512][2048]
#define WT_BASE  ((size_t)9437184)
#define WTK_OFF  (WT_BASE)                       // [1024][512]
#define WTQ_OFF  (WT_BASE + (size_t)524288)
#define WTG1_OFF (WT_BASE + (size_t)1048576)
#define WTG2_OFF (WT_BASE + (size_t)1572864)
#define WTV_OFF  (WT_BASE + (size_t)2097152)     // [512][512]
// total: 11,796,480 bf16 elems = 23.6 MB

// Transpose + convert W[k][n] fp32 -> Wt[n][k] bf16, all 5 weights in one launch.
__global__ __launch_bounds__(256)
void wtrans_kernel(const float* __restrict__ WK, const float* __restrict__ WQ,
                   const float* __restrict__ WG1, const float* __restrict__ WG2,
                   const float* __restrict__ WV, bf16* __restrict__ ws)
{
  __shared__ float T[32][33];
  const float* W; unsigned short* Wt; int N;
  switch (blockIdx.z) {
    case 0:  W = WK;  Wt = (unsigned short*)(ws + WTK_OFF);  N = 1024; break;
    case 1:  W = WQ;  Wt = (unsigned short*)(ws + WTQ_OFF);  N = 1024; break;
    case 2:  W = WG1; Wt = (unsigned short*)(ws + WTG1_OFF); N = 1024; break;
    case 3:  W = WG2; Wt = (unsigned short*)(ws + WTG2_OFF); N = 1024; break;
    default: W = WV;  Wt = (unsigned short*)(ws + WTV_OFF);  N = 512;  break;
  }
  int n0 = blockIdx.x * 32, k0 = blockIdx.y * 32;
  if (n0 >= N) return;
  int tid = threadIdx.x;
  int kk = tid >> 3, nn = (tid & 7) * 4;
  float4 v = *(const float4*)(W + (size_t)(k0 + kk) * N + n0 + nn);
  T[kk][nn] = v.x; T[kk][nn + 1] = v.y; T[kk][nn + 2] = v.z; T[kk][nn + 3] = v.w;
  __syncthreads();
  int n2 = tid >> 3, k2 = (tid & 7) * 4;
  uint2 pw;
  pw.x = pack2(T[k2][n2],     T[k2 + 1][n2]);
  pw.y = pack2(T[k2 + 2][n2], T[k2 + 3][n2]);
  *(uint2*)(Wt + (size_t)(n0 + n2) * 512 + k0 + k2) = pw;
}

// Batched MFMA projection GEMM: C = X[2048,512] @ Wt[N,512]^T + bias, bf16 out.
// 128x128 tile, BK=32, 4 waves each 64x64 (wm/wn quadrant — MUST appear in the
// epilogue addressing too; round-3 bug was omitting it there).
__global__ __launch_bounds__(256)
void proj_mfma_kernel(const float* __restrict__ fa, const float* __restrict__ fp,
                      const float* __restrict__ sa, const float* __restrict__ sp,
                      const float* __restrict__ bKp, const float* __restrict__ bQp,
                      const float* __restrict__ bG1p, const float* __restrict__ bG2p,
                      const float* __restrict__ bVp, bf16* __restrict__ ws)
{
  __shared__ short Xs[128][40];   // stride 80B = 20 dwords -> 2-way (free) frag reads
  __shared__ short Wsh[128][40];
  const float* X; const unsigned short* Wt; const float* bias; unsigned short* C;
  int N; bool trans = false;
  switch (blockIdx.z) {
    case 0:  X = fa; Wt = (const unsigned short*)(ws + WTK_OFF);  bias = bKp;  C = (unsigned short*)(ws + KB_OFF); N = 1024; break;
    case 1:  X = sa; Wt = (const unsigned short*)(ws + WTQ_OFF);  bias = bQp;  C = (unsigned short*)(ws + QB_OFF); N = 1024; break;
    case 2:  X = fp; Wt = (const unsigned short*)(ws + WTG1_OFF); bias = bG1p; C = (unsigned short*)(ws + G1_OFF); N = 1024; break;
    case 3:  X = sp; Wt = (const unsigned short*)(ws + WTG2_OFF); bias = bG2p; C = (unsigned short*)(ws + G2_OFF); N = 1024; break;
    default: X = fa; Wt = (const unsigned short*)(ws + WTV_OFF);  bias = bVp;  C = (unsigned short*)(ws + VT_OFF); N = 512; trans = true; break;
  }
  const int n0 = blockIdx.x * 128;
  if (n0 >= N) return;
  const int m0 = blockIdx.y * 128;
  const int tid = threadIdx.x;
  const int w = tid >> 6, l = tid & 63, l15 = l & 15, l4 = l >> 4;
  const int wm = (w & 1) * 64, wn = (w >> 1) * 64;
  const int srow = tid >> 1, shalf = (tid & 1) * 16;

  const float* xp = X + (size_t)(m0 + srow) * 512 + shalf;
  const unsigned short* wp = Wt + (size_t)(n0 + srow) * 512 + shalf;

  const f32x4 zero = {0.f, 0.f, 0.f, 0.f};
  f32x4 acc[4][4];
#pragma unroll
  for (int i = 0; i < 4; ++i)
#pragma unroll
    for (int j = 0; j < 4; ++j) acc[i][j] = zero;

  float4 px[4]; uint4 pw0, pw1;
  auto ldg = [&](int kc) {
    px[0] = *(const float4*)(xp + kc);
    px[1] = *(const float4*)(xp + kc + 4);
    px[2] = *(const float4*)(xp + kc + 8);
    px[3] = *(const float4*)(xp + kc + 12);
    pw0 = *(const uint4*)(wp + kc);
    pw1 = *(const uint4*)(wp + kc + 8);
  };
  ldg(0);

  for (int kc = 0; kc < 512; kc += 32) {
    __syncthreads();
    uint4 xa, xb;
    xa.x = pack2(px[0].x, px[0].y); xa.y = pack2(px[0].z, px[0].w);
    xa.z = pack2(px[1].x, px[1].y); xa.w = pack2(px[1].z, px[1].w);
    xb.x = pack2(px[2].x, px[2].y); xb.y = pack2(px[2].z, px[2].w);
    xb.z = pack2(px[3].x, px[3].y); xb.w = pack2(px[3].z, px[3].w);
    *(uint4*)&Xs[srow][shalf]      = xa;
    *(uint4*)&Xs[srow][shalf + 8]  = xb;
    *(uint4*)&Wsh[srow][shalf]     = pw0;
    *(uint4*)&Wsh[srow][shalf + 8] = pw1;
    __syncthreads();
    if (kc + 32 < 512) ldg(kc + 32);

    short8 xf[4], wf[4];
#pragma unroll
    for (int t = 0; t < 4; ++t) {
      xf[t] = *(const short8*)&Xs[wm + t * 16 + l15][l4 * 8];
      wf[t] = *(const short8*)&Wsh[wn + t * 16 + l15][l4 * 8];
    }
    if (!trans) {
#pragma unroll
      for (int i = 0; i < 4; ++i)
#pragma unroll
        for (int j = 0; j < 4; ++j)
          acc[i][j] = MFMA(wf[i], xf[j], acc[i][j]);   // D[n][m]
    } else {
#pragma unroll
      for (int i = 0; i < 4; ++i)
#pragma unroll
        for (int j = 0; j < 4; ++j)
          acc[i][j] = MFMA(xf[i], wf[j], acc[i][j]);   // D[m][n]
    }
  }

  if (!trans) {
    // acc[tn][tm]: n = n0+wn+tn*16+l4*4+r, m = m0+wm+tm*16+l15
#pragma unroll
    for (int tn = 0; tn < 4; ++tn) {
      float4 b4 = *(const float4*)(bias + n0 + wn + tn * 16 + l4 * 4);
#pragma unroll
      for (int tm = 0; tm < 4; ++tm) {
        uint2 pw;
        pw.x = pack2(acc[tn][tm][0] + b4.x, acc[tn][tm][1] + b4.y);
        pw.y = pack2(acc[tn][tm][2] + b4.z, acc[tn][tm][3] + b4.w);
        *(uint2*)(C + (size_t)(m0 + wm + tm * 16 + l15) * N + n0 + wn + tn * 16 + l4 * 4) = pw;
      }
    }
  } else {
    // acc[tm][tn]: m = m0+wm+tm*16+l4*4+r, n = n0+wn+tn*16+l15; store V^T[n][m]
#pragma unroll
    for (int tn = 0; tn < 4; ++tn) {
      float bn = bias[n0 + wn + tn * 16 + l15];
#pragma unroll
      for (int tm = 0; tm < 4; ++tm) {
        uint2 pw;
        pw.x = pack2(acc[tm][tn][0] + bn, acc[tm][tn][1] + bn);
        pw.y = pack2(acc[tm][tn][2] + bn, acc[tm][tn][3] + bn);
        *(uint2*)(C + (size_t)(n0 + wn + tn * 16 + l15) * 2048 + m0 + wm + tm * 16 + l4 * 4) = pw;
      }
    }
  }
}

// MFMA fused attention (unchanged; verified round 2).
__global__ __launch_bounds__(256)
void attn_mfma_kernel(const bf16* __restrict__ Kb, const bf16* __restrict__ G1b,
                      const bf16* __restrict__ Vtg, const bf16* __restrict__ Qb,
                      const bf16* __restrict__ G2b, float* __restrict__ out)
{
  __shared__ short Ks[64][136];
  __shared__ short G1s[64][136];
  __shared__ short Vts[64][72];
  __shared__ short Ps[4][64][20];
  __shared__ float scaleS[64];
  __shared__ float Vp[64][4];
  __shared__ float Vsum[64];

  const int tid = threadIdx.x;
  const int w   = tid >> 6;
  const int l   = tid & 63;
  const int l15 = l & 15;
  const int l4  = l >> 4;
  const int h   = blockIdx.y;
  const int m0  = blockIdx.x * 64;

  short8 qf[4], gf[4];
  {
    const size_t ro = (size_t)(m0 + w * 16 + l15) * 1024 + h * 128 + l4 * 8;
#pragma unroll
    for (int kk = 0; kk < 4; ++kk) {
      qf[kk] = *(const short8*)(Qb + ro + kk * 32);
      gf[kk] = *(const short8*)(G2b + ro + kk * 32);
    }
  }
  {
    float sq = 0.f, sg = 0.f;
#pragma unroll
    for (int kk = 0; kk < 4; ++kk)
#pragma unroll
      for (int j = 0; j < 8; ++j) {
        float q = b2f((unsigned short)qf[kk][j]);
        float g = b2f((unsigned short)gf[kk][j]);
        sq += q * q; sg += g * g;
      }
    sq += __shfl_xor(sq, 16, 64); sq += __shfl_xor(sq, 32, 64);
    sg += __shfl_xor(sg, 16, 64); sg += __shfl_xor(sg, 32, 64);
    float sc = rsqrtf(sq) * rsqrtf(sg) * (1.0f / 16384.0f);
    if (l < 16) scaleS[w * 16 + l] = sc;
  }

  const int r0 = tid >> 3, c0 = (tid & 7) * 16;
  const int jv = tid >> 2, nv = (tid & 3) * 16;

  short8 pk[4], pg[4], pv0, pv1;
  auto load_tile = [&](int nt) {
    const int n0 = nt * 64;
    const bf16* kp = Kb  + (size_t)(n0 + r0) * 1024 + h * 128 + c0;
    const bf16* gp = G1b + (size_t)(n0 + r0) * 1024 + h * 128 + c0;
    pk[0] = *(const short8*)(kp);
    pk[1] = *(const short8*)(kp + 8);
    pk[2] = *(const short8*)(kp + 32 * 1024);
    pk[3] = *(const short8*)(kp + 32 * 1024 + 8);
    pg[0] = *(const short8*)(gp);
    pg[1] = *(const short8*)(gp + 8);
    pg[2] = *(const short8*)(gp + 32 * 1024);
    pg[3] = *(const short8*)(gp + 32 * 1024 + 8);
    const bf16* vp = Vtg + (size_t)(h * 64 + jv) * 2048 + n0 + nv;
    pv0 = *(const short8*)(vp);
    pv1 = *(const short8*)(vp + 8);
  };
  load_tile(0);

  const f32x4 zero = {0.f, 0.f, 0.f, 0.f};
  f32x4 accO[4], accD = zero;
#pragma unroll
  for (int t = 0; t < 4; ++t) accO[t] = zero;
  float vsum_part = 0.f;

  short8 ones;
#pragma unroll
  for (int j = 0; j < 8; ++j) ones[j] = (short)0x3F80;

  f32x4 s4 = zero;

  for (int nt = 0; nt < 32; ++nt) {
    __syncthreads();
    *(short8*)&Ks[r0][c0]           = pk[0];
    *(short8*)&Ks[r0][c0 + 8]       = pk[1];
    *(short8*)&Ks[r0 + 32][c0]      = pk[2];
    *(short8*)&Ks[r0 + 32][c0 + 8]  = pk[3];
    *(short8*)&G1s[r0][c0]          = pg[0];
    *(short8*)&G1s[r0][c0 + 8]      = pg[1];
    *(short8*)&G1s[r0 + 32][c0]     = pg[2];
    *(short8*)&G1s[r0 + 32][c0 + 8] = pg[3];
    *(short8*)&Vts[jv][nv]          = pv0;
    *(short8*)&Vts[jv][nv + 8]      = pv1;
#pragma unroll
    for (int j = 0; j < 8; ++j)
      vsum_part += b2f((unsigned short)pv0[j]) + b2f((unsigned short)pv1[j]);
    __syncthreads();
    if (nt == 0) s4 = *(const f32x4*)&scaleS[w * 16 + l4 * 4];
    if (nt + 1 < 32) load_tile(nt + 1);

    f32x4 sa[4], sg2[4];
#pragma unroll
    for (int t = 0; t < 4; ++t) { sa[t] = zero; sg2[t] = zero; }
#pragma unroll
    for (int t = 0; t < 4; ++t) {
#pragma unroll
      for (int kk = 0; kk < 4; ++kk) {
        short8 kbf = *(const short8*)&Ks[t * 16 + l15][kk * 32 + l4 * 8];
        sa[t]  = MFMA(qf[kk], kbf, sa[t]);
        short8 gbf = *(const short8*)&G1s[t * 16 + l15][kk * 32 + l4 * 8];
        sg2[t] = MFMA(gf[kk], gbf, sg2[t]);
      }
    }
#pragma unroll
    for (int t = 0; t < 4; ++t) {
      unsigned short e0 = f2bf(__expf(sa[t][0] * sg2[t][0] * s4[0]) - 1.0f);
      unsigned short e1 = f2bf(__expf(sa[t][1] * sg2[t][1] * s4[1]) - 1.0f);
      unsigned short e2 = f2bf(__expf(sa[t][2] * sg2[t][2] * s4[2]) - 1.0f);
      unsigned short e3 = f2bf(__expf(sa[t][3] * sg2[t][3] * s4[3]) - 1.0f);
      uint2 pw;
      pw.x = (unsigned)e0 | ((unsigned)e1 << 16);
      pw.y = (unsigned)e2 | ((unsigned)e3 << 16);
      *(uint2*)&Ps[w][t * 16 + l15][l4 * 4] = pw;
    }
#pragma unroll
    for (int ks = 0; ks < 2; ++ks) {
      short8 pf;
#pragma unroll
      for (int j = 0; j < 8; ++j)
        pf[j] = Ps[w][ks * 32 + l4 * 8 + j][l15];
      accD = MFMA(pf, ones, accD);
#pragma unroll
      for (int jt = 0; jt < 4; ++jt) {
        short8 vbf = *(const short8*)&Vts[jt * 16 + l15][ks * 32 + l4 * 8];
        accO[jt] = MFMA(pf, vbf, accO[jt]);
      }
    }
  }

  __syncthreads();
  Vp[jv][tid & 3] = vsum_part;
  __syncthreads();
  if (tid < 64) Vsum[tid] = Vp[tid][0] + Vp[tid][1] + Vp[tid][2] + Vp[tid][3];
  __syncthreads();

  float inv[4];
#pragma unroll
  for (int r = 0; r < 4; ++r) inv[r] = 1.0f / (2048.0f + accD[r]);
#pragma unroll
  for (int jt = 0; jt < 4; ++jt) {
    float vs = Vsum[jt * 16 + l15];
#pragma unroll
    for (int r = 0; r < 4; ++r)
      out[(size_t)(m0 + w * 16 + l4 * 4 + r) * 512 + h * 64 + jt * 16 + l15]
        = (vs + accO[jt][r]) * inv[r];
  }
}

extern "C" void kernel_launch(void* const* d_in, const int* in_sizes, int n_in,
                              void* d_out, int out_size, void* d_ws, size_t ws_size,
                              hipStream_t stream) {
  const float* first_app  = (const float*)d_in[0];
  const float* first_pos  = (const float*)d_in[1];
  const float* second_app = (const float*)d_in[2];
  const float* second_pos = (const float*)d_in[3];
  const float* WK  = (const float*)d_in[4];
  const float* bK  = (const float*)d_in[5];
  const float* WQ  = (const float*)d_in[6];
  const float* bQ  = (const float*)d_in[7];
  const float* WV  = (const float*)d_in[8];
  const float* bV  = (const float*)d_in[9];
  const float* WG1 = (const float*)d_in[10];
  const float* bG1 = (const float*)d_in[11];
  const float* WG2 = (const float*)d_in[12];
  const float* bG2 = (const float*)d_in[13];

  bf16* ws = (bf16*)d_ws;

  wtrans_kernel<<<dim3(32, 16, 5), 256, 0, stream>>>(WK, WQ, WG1, WG2, WV, ws);
  proj_mfma_kernel<<<dim3(8, 16, 5), 256, 0, stream>>>(
      first_app, first_pos, second_app, second_pos, bK, bQ, bG1, bG2, bV, ws);
  attn_mfma_kernel<<<dim3(32, 8), 256, 0, stream>>>(
      ws + KB_OFF, ws + G1_OFF, ws + VT_OFF, ws + QB_OFF, ws + G2_OFF, (float*)d_out);
}

// Round 5
// 174.191 us; speedup vs baseline: 4.3471x; 1.0509x over previous
//
#include <hip/hip_runtime.h>
#include <hip/hip_bf16.h>

typedef __hip_bfloat16 bf16;
typedef __attribute__((ext_vector_type(8))) short short8;   // 8 bf16 = one MFMA A/B frag
typedef __attribute__((ext_vector_type(4))) float f32x4;    // MFMA C/D frag

#define MFMA(a, b, c) __builtin_amdgcn_mfma_f32_16x16x32_bf16(a, b, c, 0, 0, 0)

static __device__ __forceinline__ float b2f(unsigned short u) {
  union { unsigned u; float f; } t; t.u = ((unsigned)u) << 16; return t.f;
}
static __device__ __forceinline__ unsigned short f2bf(float f) {
  union { float f; unsigned u; } t; t.f = f;
  unsigned r = t.u + 0x7fffu + ((t.u >> 16) & 1u);   // RNE
  return (unsigned short)(r >> 16);
}
static __device__ __forceinline__ unsigned pack2(float a, float b) {
  return (unsigned)f2bf(a) | ((unsigned)f2bf(b) << 16);
}

// ---- workspace layout (bf16 element offsets) ----
#define KB_OFF   ((size_t)0)          // K  [2048][1024]
#define QB_OFF   ((size_t)2097152)    // Q  [2048][1024]
#define G1_OFF   ((size_t)4194304)    // G1 [2048][1024]
#define G2_OFF   ((size_t)6291456)    // G2 [2048][1024]
#define VT_OFF   ((size_t)8388608)    // V^T [512][2048]
#define WT_BASE  ((size_t)9437184)
#define WTK_OFF  (WT_BASE)                       // [1024][512]
#define WTQ_OFF  (WT_BASE + (size_t)524288)
#define WTG1_OFF (WT_BASE + (size_t)1048576)
#define WTG2_OFF (WT_BASE + (size_t)1572864)
#define WTV_OFF  (WT_BASE + (size_t)2097152)     // [512][512]
// After proj, the WT region is dead -> reuse for attention partials:
#define NUM0_OFF (WT_BASE)                       // bf16 [2048][512] (n-split 0)
#define NUM1_OFF (WT_BASE + (size_t)1048576)     // bf16 [2048][512] (n-split 1)
#define DEN_OFF  (WT_BASE + (size_t)2097152)     // f32  [2][8][2048] (as raw bytes)
// total ws: 11,796,480 bf16 elems = 23.6 MB (unchanged)

// Transpose + convert W[k][n] fp32 -> Wt[n][k] bf16, all 5 weights in one launch.
__global__ __launch_bounds__(256)
void wtrans_kernel(const float* __restrict__ WK, const float* __restrict__ WQ,
                   const float* __restrict__ WG1, const float* __restrict__ WG2,
                   const float* __restrict__ WV, bf16* __restrict__ ws)
{
  __shared__ float T[32][33];
  const float* W; unsigned short* Wt; int N;
  switch (blockIdx.z) {
    case 0:  W = WK;  Wt = (unsigned short*)(ws + WTK_OFF);  N = 1024; break;
    case 1:  W = WQ;  Wt = (unsigned short*)(ws + WTQ_OFF);  N = 1024; break;
    case 2:  W = WG1; Wt = (unsigned short*)(ws + WTG1_OFF); N = 1024; break;
    case 3:  W = WG2; Wt = (unsigned short*)(ws + WTG2_OFF); N = 1024; break;
    default: W = WV;  Wt = (unsigned short*)(ws + WTV_OFF);  N = 512;  break;
  }
  int n0 = blockIdx.x * 32, k0 = blockIdx.y * 32;
  if (n0 >= N) return;
  int tid = threadIdx.x;
  int kk = tid >> 3, nn = (tid & 7) * 4;
  float4 v = *(const float4*)(W + (size_t)(k0 + kk) * N + n0 + nn);
  T[kk][nn] = v.x; T[kk][nn + 1] = v.y; T[kk][nn + 2] = v.z; T[kk][nn + 3] = v.w;
  __syncthreads();
  int n2 = tid >> 3, k2 = (tid & 7) * 4;
  uint2 pw;
  pw.x = pack2(T[k2][n2],     T[k2 + 1][n2]);
  pw.y = pack2(T[k2 + 2][n2], T[k2 + 3][n2]);
  *(uint2*)(Wt + (size_t)(n0 + n2) * 512 + k0 + k2) = pw;
}

// Batched MFMA projection GEMM (verified round 4).
__global__ __launch_bounds__(256)
void proj_mfma_kernel(const float* __restrict__ fa, const float* __restrict__ fp,
                      const float* __restrict__ sa, const float* __restrict__ sp,
                      const float* __restrict__ bKp, const float* __restrict__ bQp,
                      const float* __restrict__ bG1p, const float* __restrict__ bG2p,
                      const float* __restrict__ bVp, bf16* __restrict__ ws)
{
  __shared__ short Xs[128][40];
  __shared__ short Wsh[128][40];
  const float* X; const unsigned short* Wt; const float* bias; unsigned short* C;
  int N; bool trans = false;
  switch (blockIdx.z) {
    case 0:  X = fa; Wt = (const unsigned short*)(ws + WTK_OFF);  bias = bKp;  C = (unsigned short*)(ws + KB_OFF); N = 1024; break;
    case 1:  X = sa; Wt = (const unsigned short*)(ws + WTQ_OFF);  bias = bQp;  C = (unsigned short*)(ws + QB_OFF); N = 1024; break;
    case 2:  X = fp; Wt = (const unsigned short*)(ws + WTG1_OFF); bias = bG1p; C = (unsigned short*)(ws + G1_OFF); N = 1024; break;
    case 3:  X = sp; Wt = (const unsigned short*)(ws + WTG2_OFF); bias = bG2p; C = (unsigned short*)(ws + G2_OFF); N = 1024; break;
    default: X = fa; Wt = (const unsigned short*)(ws + WTV_OFF);  bias = bVp;  C = (unsigned short*)(ws + VT_OFF); N = 512; trans = true; break;
  }
  const int n0 = blockIdx.x * 128;
  if (n0 >= N) return;
  const int m0 = blockIdx.y * 128;
  const int tid = threadIdx.x;
  const int w = tid >> 6, l = tid & 63, l15 = l & 15, l4 = l >> 4;
  const int wm = (w & 1) * 64, wn = (w >> 1) * 64;
  const int srow = tid >> 1, shalf = (tid & 1) * 16;

  const float* xp = X + (size_t)(m0 + srow) * 512 + shalf;
  const unsigned short* wp = Wt + (size_t)(n0 + srow) * 512 + shalf;

  const f32x4 zero = {0.f, 0.f, 0.f, 0.f};
  f32x4 acc[4][4];
#pragma unroll
  for (int i = 0; i < 4; ++i)
#pragma unroll
    for (int j = 0; j < 4; ++j) acc[i][j] = zero;

  float4 px[4]; uint4 pw0, pw1;
  auto ldg = [&](int kc) {
    px[0] = *(const float4*)(xp + kc);
    px[1] = *(const float4*)(xp + kc + 4);
    px[2] = *(const float4*)(xp + kc + 8);
    px[3] = *(const float4*)(xp + kc + 12);
    pw0 = *(const uint4*)(wp + kc);
    pw1 = *(const uint4*)(wp + kc + 8);
  };
  ldg(0);

  for (int kc = 0; kc < 512; kc += 32) {
    __syncthreads();
    uint4 xa, xb;
    xa.x = pack2(px[0].x, px[0].y); xa.y = pack2(px[0].z, px[0].w);
    xa.z = pack2(px[1].x, px[1].y); xa.w = pack2(px[1].z, px[1].w);
    xb.x = pack2(px[2].x, px[2].y); xb.y = pack2(px[2].z, px[2].w);
    xb.z = pack2(px[3].x, px[3].y); xb.w = pack2(px[3].z, px[3].w);
    *(uint4*)&Xs[srow][shalf]      = xa;
    *(uint4*)&Xs[srow][shalf + 8]  = xb;
    *(uint4*)&Wsh[srow][shalf]     = pw0;
    *(uint4*)&Wsh[srow][shalf + 8] = pw1;
    __syncthreads();
    if (kc + 32 < 512) ldg(kc + 32);

    short8 xf[4], wf[4];
#pragma unroll
    for (int t = 0; t < 4; ++t) {
      xf[t] = *(const short8*)&Xs[wm + t * 16 + l15][l4 * 8];
      wf[t] = *(const short8*)&Wsh[wn + t * 16 + l15][l4 * 8];
    }
    if (!trans) {
#pragma unroll
      for (int i = 0; i < 4; ++i)
#pragma unroll
        for (int j = 0; j < 4; ++j)
          acc[i][j] = MFMA(wf[i], xf[j], acc[i][j]);   // D[n][m]
    } else {
#pragma unroll
      for (int i = 0; i < 4; ++i)
#pragma unroll
        for (int j = 0; j < 4; ++j)
          acc[i][j] = MFMA(xf[i], wf[j], acc[i][j]);   // D[m][n]
    }
  }

  if (!trans) {
#pragma unroll
    for (int tn = 0; tn < 4; ++tn) {
      float4 b4 = *(const float4*)(bias + n0 + wn + tn * 16 + l4 * 4);
#pragma unroll
      for (int tm = 0; tm < 4; ++tm) {
        uint2 pw;
        pw.x = pack2(acc[tn][tm][0] + b4.x, acc[tn][tm][1] + b4.y);
        pw.y = pack2(acc[tn][tm][2] + b4.z, acc[tn][tm][3] + b4.w);
        *(uint2*)(C + (size_t)(m0 + wm + tm * 16 + l15) * N + n0 + wn + tn * 16 + l4 * 4) = pw;
      }
    }
  } else {
#pragma unroll
    for (int tn = 0; tn < 4; ++tn) {
      float bn = bias[n0 + wn + tn * 16 + l15];
#pragma unroll
      for (int tm = 0; tm < 4; ++tm) {
        uint2 pw;
        pw.x = pack2(acc[tm][tn][0] + bn, acc[tm][tn][1] + bn);
        pw.y = pack2(acc[tm][tn][2] + bn, acc[tm][tn][3] + bn);
        *(uint2*)(C + (size_t)(n0 + wn + tn * 16 + l15) * 2048 + m0 + wm + tm * 16 + l4 * 4) = pw;
      }
    }
  }
}

// MFMA fused attention, n-split=2 for occupancy (2 blocks/CU, 2 waves/SIMD).
// Each block: half the n-range (16 iters of 64). Writes partial numerator
// (vsum_half + P'V, bf16) and partial denominator (sum P', f32) to ws.
// exp(x)-1 computed as x + x^2/2 (|x| ~ 1e-4; cubic error ~1e-12).
__global__ __launch_bounds__(256)
void attn_mfma_kernel(const bf16* __restrict__ Kb, const bf16* __restrict__ G1b,
                      const bf16* __restrict__ Vtg, const bf16* __restrict__ Qb,
                      const bf16* __restrict__ G2b, bf16* __restrict__ ws)
{
  __shared__ short Ks[64][136];
  __shared__ short G1s[64][136];
  __shared__ short Vts[64][72];
  __shared__ short Ps[4][64][20];
  __shared__ float scaleS[64];
  __shared__ float Vp[64][4];
  __shared__ float Vsum[64];

  const int tid = threadIdx.x;
  const int w   = tid >> 6;
  const int l   = tid & 63;
  const int l15 = l & 15;
  const int l4  = l >> 4;
  const int h   = blockIdx.y;
  const int m0  = blockIdx.x * 64;
  const int split = blockIdx.z;

  short8 qf[4], gf[4];
  {
    const size_t ro = (size_t)(m0 + w * 16 + l15) * 1024 + h * 128 + l4 * 8;
#pragma unroll
    for (int kk = 0; kk < 4; ++kk) {
      qf[kk] = *(const short8*)(Qb + ro + kk * 32);
      gf[kk] = *(const short8*)(G2b + ro + kk * 32);
    }
  }
  {
    float sq = 0.f, sg = 0.f;
#pragma unroll
    for (int kk = 0; kk < 4; ++kk)
#pragma unroll
      for (int j = 0; j < 8; ++j) {
        float q = b2f((unsigned short)qf[kk][j]);
        float g = b2f((unsigned short)gf[kk][j]);
        sq += q * q; sg += g * g;
      }
    sq += __shfl_xor(sq, 16, 64); sq += __shfl_xor(sq, 32, 64);
    sg += __shfl_xor(sg, 16, 64); sg += __shfl_xor(sg, 32, 64);
    float sc = rsqrtf(sq) * rsqrtf(sg) * (1.0f / 16384.0f);
    if (l < 16) scaleS[w * 16 + l] = sc;
  }

  const int r0 = tid >> 3, c0 = (tid & 7) * 16;
  const int jv = tid >> 2, nv = (tid & 3) * 16;

  short8 pk[4], pg[4], pv0, pv1;
  auto load_tile = [&](int nt) {       // nt in global 64-units
    const int n0 = nt * 64;
    const bf16* kp = Kb  + (size_t)(n0 + r0) * 1024 + h * 128 + c0;
    const bf16* gp = G1b + (size_t)(n0 + r0) * 1024 + h * 128 + c0;
    pk[0] = *(const short8*)(kp);
    pk[1] = *(const short8*)(kp + 8);
    pk[2] = *(const short8*)(kp + 32 * 1024);
    pk[3] = *(const short8*)(kp + 32 * 1024 + 8);
    pg[0] = *(const short8*)(gp);
    pg[1] = *(const short8*)(gp + 8);
    pg[2] = *(const short8*)(gp + 32 * 1024);
    pg[3] = *(const short8*)(gp + 32 * 1024 + 8);
    const bf16* vp = Vtg + (size_t)(h * 64 + jv) * 2048 + n0 + nv;
    pv0 = *(const short8*)(vp);
    pv1 = *(const short8*)(vp + 8);
  };
  const int ntbase = split * 16;
  load_tile(ntbase);

  const f32x4 zero = {0.f, 0.f, 0.f, 0.f};
  f32x4 accO[4], accD = zero;
#pragma unroll
  for (int t = 0; t < 4; ++t) accO[t] = zero;
  float vsum_part = 0.f;

  short8 ones;
#pragma unroll
  for (int j = 0; j < 8; ++j) ones[j] = (short)0x3F80;

  f32x4 s4 = zero;

  for (int nt = 0; nt < 16; ++nt) {
    __syncthreads();
    *(short8*)&Ks[r0][c0]           = pk[0];
    *(short8*)&Ks[r0][c0 + 8]       = pk[1];
    *(short8*)&Ks[r0 + 32][c0]      = pk[2];
    *(short8*)&Ks[r0 + 32][c0 + 8]  = pk[3];
    *(short8*)&G1s[r0][c0]          = pg[0];
    *(short8*)&G1s[r0][c0 + 8]      = pg[1];
    *(short8*)&G1s[r0 + 32][c0]     = pg[2];
    *(short8*)&G1s[r0 + 32][c0 + 8] = pg[3];
    *(short8*)&Vts[jv][nv]          = pv0;
    *(short8*)&Vts[jv][nv + 8]      = pv1;
#pragma unroll
    for (int j = 0; j < 8; ++j)
      vsum_part += b2f((unsigned short)pv0[j]) + b2f((unsigned short)pv1[j]);
    __syncthreads();
    if (nt == 0) s4 = *(const f32x4*)&scaleS[w * 16 + l4 * 4];
    if (nt + 1 < 16) load_tile(ntbase + nt + 1);

    f32x4 sa[4], sg2[4];
#pragma unroll
    for (int t = 0; t < 4; ++t) { sa[t] = zero; sg2[t] = zero; }
#pragma unroll
    for (int t = 0; t < 4; ++t) {
#pragma unroll
      for (int kk = 0; kk < 4; ++kk) {
        short8 kbf = *(const short8*)&Ks[t * 16 + l15][kk * 32 + l4 * 8];
        sa[t]  = MFMA(qf[kk], kbf, sa[t]);
        short8 gbf = *(const short8*)&G1s[t * 16 + l15][kk * 32 + l4 * 8];
        sg2[t] = MFMA(gf[kk], gbf, sg2[t]);
      }
    }
    // P' = exp(x)-1 ~= x + x^2/2
#pragma unroll
    for (int t = 0; t < 4; ++t) {
      float x0 = sa[t][0] * sg2[t][0] * s4[0];
      float x1 = sa[t][1] * sg2[t][1] * s4[1];
      float x2 = sa[t][2] * sg2[t][2] * s4[2];
      float x3 = sa[t][3] * sg2[t][3] * s4[3];
      unsigned short e0 = f2bf(__builtin_fmaf(0.5f * x0, x0, x0));
      unsigned short e1 = f2bf(__builtin_fmaf(0.5f * x1, x1, x1));
      unsigned short e2 = f2bf(__builtin_fmaf(0.5f * x2, x2, x2));
      unsigned short e3 = f2bf(__builtin_fmaf(0.5f * x3, x3, x3));
      uint2 pw;
      pw.x = (unsigned)e0 | ((unsigned)e1 << 16);
      pw.y = (unsigned)e2 | ((unsigned)e3 << 16);
      *(uint2*)&Ps[w][t * 16 + l15][l4 * 4] = pw;
    }
#pragma unroll
    for (int ks = 0; ks < 2; ++ks) {
      short8 pf;
#pragma unroll
      for (int j = 0; j < 8; ++j)
        pf[j] = Ps[w][ks * 32 + l4 * 8 + j][l15];
      accD = MFMA(pf, ones, accD);
#pragma unroll
      for (int jt = 0; jt < 4; ++jt) {
        short8 vbf = *(const short8*)&Vts[jt * 16 + l15][ks * 32 + l4 * 8];
        accO[jt] = MFMA(pf, vbf, accO[jt]);
      }
    }
  }

  __syncthreads();
  Vp[jv][tid & 3] = vsum_part;
  __syncthreads();
  if (tid < 64) Vsum[tid] = Vp[tid][0] + Vp[tid][1] + Vp[tid][2] + Vp[tid][3];
  __syncthreads();

  // ---- write partials ----
  bf16* num = ws + (split ? NUM1_OFF : NUM0_OFF);
  float* den = (float*)(ws + DEN_OFF);
  if (l15 == 0) {
#pragma unroll
    for (int r = 0; r < 4; ++r)
      den[(size_t)(split * 8 + h) * 2048 + m0 + w * 16 + l4 * 4 + r] = accD[r];
  }
#pragma unroll
  for (int jt = 0; jt < 4; ++jt) {
    float vs = Vsum[jt * 16 + l15];
#pragma unroll
    for (int r = 0; r < 4; ++r)
      num[(size_t)(m0 + w * 16 + l4 * 4 + r) * 512 + h * 64 + jt * 16 + l15]
        = __float2bfloat16(vs + accO[jt][r]);
  }
}

// out[m][c] = (num0+num1) / (2048 + den0 + den1), c = h*64+j
__global__ __launch_bounds__(256)
void combine_kernel(const bf16* __restrict__ ws, float* __restrict__ out)
{
  const bf16* num0 = ws + NUM0_OFF;
  const bf16* num1 = ws + NUM1_OFF;
  const float* den = (const float*)(ws + DEN_OFF);
  int idx = blockIdx.x * 256 + threadIdx.x;
  int m = idx >> 9, c = idx & 511, h = c >> 6;
  float d = 2048.0f + den[(size_t)h * 2048 + m] + den[(size_t)(8 + h) * 2048 + m];
  float n = b2f(((const unsigned short*)num0)[idx]) + b2f(((const unsigned short*)num1)[idx]);
  out[idx] = n / d;
}

extern "C" void kernel_launch(void* const* d_in, const int* in_sizes, int n_in,
                              void* d_out, int out_size, void* d_ws, size_t ws_size,
                              hipStream_t stream) {
  const float* first_app  = (const float*)d_in[0];
  const float* first_pos  = (const float*)d_in[1];
  const float* second_app = (const float*)d_in[2];
  const float* second_pos = (const float*)d_in[3];
  const float* WK  = (const float*)d_in[4];
  const float* bK  = (const float*)d_in[5];
  const float* WQ  = (const float*)d_in[6];
  const float* bQ  = (const float*)d_in[7];
  const float* WV  = (const float*)d_in[8];
  const float* bV  = (const float*)d_in[9];
  const float* WG1 = (const float*)d_in[10];
  const float* bG1 = (const float*)d_in[11];
  const float* WG2 = (const float*)d_in[12];
  const float* bG2 = (const float*)d_in[13];

  bf16* ws = (bf16*)d_ws;

  wtrans_kernel<<<dim3(32, 16, 5), 256, 0, stream>>>(WK, WQ, WG1, WG2, WV, ws);
  proj_mfma_kernel<<<dim3(8, 16, 5), 256, 0, stream>>>(
      first_app, first_pos, second_app, second_pos, bK, bQ, bG1, bG2, bV, ws);
  attn_mfma_kernel<<<dim3(32, 8, 2), 256, 0, stream>>>(
      ws + KB_OFF, ws + G1_OFF, ws + VT_OFF, ws + QB_OFF, ws + G2_OFF, ws);
  combine_kernel<<<dim3(4096), 256, 0, stream>>>(ws, (float*)d_out);
}